// Round 9
// baseline (5911.864 us; speedup 1.0000x reference)
//
#include <hip/hip_runtime.h>
#include <hip/hip_bf16.h>
#include <math.h>

typedef __attribute__((ext_vector_type(8))) short s16x8;
typedef __attribute__((ext_vector_type(4))) short s16x4;
typedef __attribute__((ext_vector_type(4))) float f32x4;

#define MP 12672        // padded token rows: 99*128 (real 64*197=12608)
#define MREAL 12608
#define PROWS 12544     // 64*196 patch rows
#define SCALE 0.125f

__device__ __forceinline__ float gelu_exact(float z) {
    return 0.5f * z * (1.f + erff(z * 0.7071067811865475f));
}

// ---------------- small utility kernels ----------------
__global__ void zero_pad_rows(float* __restrict__ x) {
    int r = MREAL + blockIdx.x;
    x[(size_t)r * 768 + threadIdx.x] = 0.f;
}

__global__ void set_cls(const float* __restrict__ cls, const float* __restrict__ pos,
                        float* __restrict__ x) {
    int b = blockIdx.x, t = threadIdx.x;
    x[(size_t)b * 197 * 768 + t] = cls[t] + pos[t];
}

__global__ void cast_pw(const float* __restrict__ w, __hip_bfloat16* __restrict__ o, int n) {
    int i = blockIdx.x * 256 + threadIdx.x;
    if (i < n) o[i] = __float2bfloat16(w[i]);
}

__global__ void im2col_kernel(const float* __restrict__ img, __hip_bfloat16* __restrict__ P) {
    int row = blockIdx.x;
    int t = threadIdx.x;
    if (row >= PROWS) {
        for (int k = t; k < 768; k += 256) P[(size_t)row * 768 + k] = __float2bfloat16(0.f);
        return;
    }
    int b = row / 196, n = row % 196;
    int gh = n / 14, gw = n % 14;
    for (int k = t; k < 768; k += 256) {
        int c = k >> 8, rem = k & 255, p = rem >> 4, q = rem & 15;
        float v = img[((size_t)(b * 3 + c) * 224 + (gh * 16 + p)) * 224 + gw * 16 + q];
        P[(size_t)row * 768 + k] = __float2bfloat16(v);
    }
}

// all 4 per-layer weight transposes in ONE launch (6912 blocks of 32x8)
__global__ void transpose_cast_all(const float* __restrict__ qkvw,
                                   const float* __restrict__ projw,
                                   const float* __restrict__ fc1w,
                                   const float* __restrict__ fc2w,
                                   __hip_bfloat16* __restrict__ wt) {
    __shared__ float tile[32][33];
    int bid = blockIdx.x;
    const float* W; __hip_bfloat16* D; int K, N, tn;
    if (bid < 1728) { W = qkvw; D = wt; K = 768; N = 2304; tn = 72; }
    else if (bid < 2304) { bid -= 1728; W = projw; D = wt + 1769472; K = 768; N = 768; tn = 24; }
    else if (bid < 4608) { bid -= 2304; W = fc1w; D = wt + 2359296; K = 768; N = 3072; tn = 96; }
    else { bid -= 4608; W = fc2w; D = wt + 4718592; K = 3072; N = 768; tn = 24; }
    int n0 = (bid % tn) * 32, k0 = (bid / tn) * 32;
    int tx = threadIdx.x, ty = threadIdx.y;
    #pragma unroll
    for (int i = 0; i < 4; ++i)
        tile[ty + i * 8][tx] = W[(size_t)(k0 + ty + i * 8) * N + n0 + tx];
    __syncthreads();
    #pragma unroll
    for (int i = 0; i < 4; ++i)
        D[(size_t)(n0 + ty + i * 8) * K + k0 + tx] = __float2bfloat16(tile[tx][ty + i * 8]);
}

// ---------------- layernorm (block per row; round-6 proven) ----------------
__global__ void ln_bf16(const float* __restrict__ x, const float* __restrict__ g,
                        const float* __restrict__ bia, __hip_bfloat16* __restrict__ y) {
    int row = blockIdx.x;
    const float* xr = x + (size_t)row * 768;
    __hip_bfloat16* yr = y + (size_t)row * 768;
    int t = threadIdx.x;
    float v[3];
    float s = 0.f, s2 = 0.f;
    #pragma unroll
    for (int i = 0; i < 3; ++i) { v[i] = xr[t + 256 * i]; s += v[i]; s2 += v[i] * v[i]; }
    __shared__ float r1[256], r2[256];
    r1[t] = s; r2[t] = s2; __syncthreads();
    for (int off = 128; off > 0; off >>= 1) {
        if (t < off) { r1[t] += r1[t + off]; r2[t] += r2[t + off]; }
        __syncthreads();
    }
    float mean = r1[0] * (1.f / 768.f);
    float var = r2[0] * (1.f / 768.f) - mean * mean;
    float rs = rsqrtf(var + 1e-6f);
    #pragma unroll
    for (int i = 0; i < 3; ++i) {
        int c = t + 256 * i;
        yr[c] = __float2bfloat16((v[i] - mean) * rs * g[c] + bia[c]);
    }
}

// final LN on the 64 CLS rows, output TRANSPOSED fp32 At[768][64]
__global__ void ln_cls_t(const float* __restrict__ x, const float* __restrict__ g,
                         const float* __restrict__ bia, float* __restrict__ At) {
    int b = blockIdx.x;
    const float* xr = x + (size_t)b * 197 * 768;
    int t = threadIdx.x;
    float v[3];
    float s = 0.f, s2 = 0.f;
    #pragma unroll
    for (int i = 0; i < 3; ++i) { v[i] = xr[t + 256 * i]; s += v[i]; s2 += v[i] * v[i]; }
    __shared__ float r1[256], r2[256];
    r1[t] = s; r2[t] = s2; __syncthreads();
    for (int off = 128; off > 0; off >>= 1) {
        if (t < off) { r1[t] += r1[t + off]; r2[t] += r2[t + off]; }
        __syncthreads();
    }
    float mean = r1[0] * (1.f / 768.f);
    float var = r2[0] * (1.f / 768.f) - mean * mean;
    float rs = rsqrtf(var + 1e-6f);
    #pragma unroll
    for (int i = 0; i < 3; ++i) {
        int c = t + 256 * i;
        At[(size_t)c * 64 + b] = (v[i] - mean) * rs * g[c] + bia[c];
    }
}

// ---------------- bf16 MFMA GEMM (round-6 proven structure; K now COMPILE-TIME) ----------------
// EPI: 0 = bias -> f32   1 = bias + res -> f32   2 = bias + gelu -> bf16
//      3 = patch-embed remap (+pos) -> f32       4 = bias -> bf16
template <int EPI, int KC>
__global__ __launch_bounds__(256)
void gemm_mfma(const __hip_bfloat16* __restrict__ A,
               const __hip_bfloat16* __restrict__ Bt,
               const float* __restrict__ bias,
               const float* res, float* Cf, __hip_bfloat16* Cb,
               const float* __restrict__ pos,
               int Nc) {
    __shared__ short As[8192];
    __shared__ short Bs[8192];
    int tid = threadIdx.x;
    int lane = tid & 63, w = tid >> 6;
    int wr = w >> 1, wc = w & 1;
    // XCD-aware bijective block swizzle (m204)
    int nwg = gridDim.x * gridDim.y;
    int bid = blockIdx.y * gridDim.x + blockIdx.x;
    int xcd = bid & 7, idx = bid >> 3;
    int qq = nwg >> 3, rr = nwg & 7;
    int swz = (xcd < rr ? xcd * (qq + 1) : rr * (qq + 1) + (xcd - rr) * qq) + idx;
    int bm = (swz / gridDim.x) * 128, bn = (swz % gridDim.x) * 128;
    int l15 = lane & 15, lh = lane >> 4;
    f32x4 acc[4][4] = {};
    for (int k0 = 0; k0 < KC; k0 += 64) {
        #pragma unroll
        for (int q = 0; q < 4; ++q) {
            int S = (w * 4 + q) * 64 + lane;
            int row = S >> 3;
            int c = (S & 7) ^ (row & 7);
            const __hip_bfloat16* sA = A + (size_t)(bm + row) * KC + (k0 + c * 8);
            const __hip_bfloat16* sB = Bt + (size_t)(bn + row) * KC + (k0 + c * 8);
            __builtin_amdgcn_global_load_lds(
                (const __attribute__((address_space(1))) void*)sA,
                (__attribute__((address_space(3))) void*)&As[(w * 4 + q) * 512], 16, 0, 0);
            __builtin_amdgcn_global_load_lds(
                (const __attribute__((address_space(1))) void*)sB,
                (__attribute__((address_space(3))) void*)&Bs[(w * 4 + q) * 512], 16, 0, 0);
        }
        __syncthreads();
        #pragma unroll
        for (int ks = 0; ks < 2; ++ks) {
            s16x8 av[4], bv[4];
            int c = ks * 4 + lh;
            #pragma unroll
            for (int i = 0; i < 4; ++i) {
                int ra = wr * 64 + i * 16 + l15;
                av[i] = *(const s16x8*)&As[(ra * 8 + (c ^ (ra & 7))) * 8];
                int rb = wc * 64 + i * 16 + l15;
                bv[i] = *(const s16x8*)&Bs[(rb * 8 + (c ^ (rb & 7))) * 8];
            }
            #pragma unroll
            for (int i = 0; i < 4; ++i)
                #pragma unroll
                for (int j = 0; j < 4; ++j)
                    acc[i][j] = __builtin_amdgcn_mfma_f32_16x16x32_bf16(av[i], bv[j], acc[i][j], 0, 0, 0);
        }
        __syncthreads();
    }
    #pragma unroll
    for (int i = 0; i < 4; ++i) {
        #pragma unroll
        for (int j = 0; j < 4; ++j) {
            int colg = bn + wc * 64 + j * 16 + l15;
            float bcol = bias[colg];
            #pragma unroll
            for (int r = 0; r < 4; ++r) {
                int rowg = bm + wr * 64 + i * 16 + lh * 4 + r;
                float v = acc[i][j][r] + bcol;
                if (EPI == 0) {
                    Cf[(size_t)rowg * Nc + colg] = v;
                } else if (EPI == 1) {
                    Cf[(size_t)rowg * Nc + colg] = v + res[(size_t)rowg * Nc + colg];
                } else if (EPI == 2) {
                    Cb[(size_t)rowg * Nc + colg] = __float2bfloat16(gelu_exact(v));
                } else if (EPI == 4) {
                    Cb[(size_t)rowg * Nc + colg] = __float2bfloat16(v);
                } else {
                    if (rowg < PROWS) {
                        int b = rowg / 196, n = rowg % 196;
                        Cf[((size_t)b * 197 + 1 + n) * 768 + colg] = v + pos[(size_t)(1 + n) * 768 + colg];
                    }
                }
            }
        }
    }
}

// ---------------- MFMA flash attention (round-6 proven; no setprio) ----------------
// grid (h=12, b=64), 256 threads = 4 waves. Swapped QK^T; 4-lane softmax reduce.
__global__ __launch_bounds__(256)
void attn_mfma(const __hip_bfloat16* __restrict__ qkvp, const int* __restrict__ key_mask,
               __hip_bfloat16* __restrict__ o, float* __restrict__ cls_row,
               int useMask, int saveCls) {
    int h = blockIdx.x, b = blockIdx.y;
    __shared__ short Kl[224 * 64];
    __shared__ short Vt[64 * 256];
    __shared__ short Pl[4][4096];
    __shared__ unsigned mword[7];
    const short* qkv = (const short*)qkvp;
    int t = threadIdx.x;

    if (t < 7) {
        unsigned wb = 0;
        for (int j = 0; j < 32; ++j) {
            int k = t * 32 + j;
            int bit = (k < 197) ? (useMask ? (key_mask[b * 197 + k] != 0) : 1) : 0;
            wb |= (unsigned)bit << j;
        }
        mword[t] = wb;
    }
    {
        int c = t & 7, kr0 = t >> 3;
        for (int it = 0; it < 7; ++it) {
            int krow = kr0 + it * 32;
            s16x8 v;
            if (krow < 197) {
                v = *(const s16x8*)(qkv + (size_t)(b * 197 + krow) * 2304 + 768 + h * 64 + c * 8);
            } else {
                #pragma unroll
                for (int j = 0; j < 8; ++j) v[j] = 0;
            }
            *(s16x8*)&Kl[(krow * 8 + (c ^ (krow & 7))) * 8] = v;
        }
    }
    {
        int d = t & 63, cb = t >> 6;
        for (int it = 0; it < 8; ++it) {
            int c = cb + it * 4;
            s16x8 v;
            #pragma unroll
            for (int j = 0; j < 8; ++j) {
                int k = c * 8 + j;
                v[j] = (k < 197) ? qkv[(size_t)(b * 197 + k) * 2304 + 1536 + h * 64 + d] : (short)0;
            }
            *(s16x8*)&Vt[(d * 32 + (c ^ (d & 7))) * 8] = v;
        }
    }
    __syncthreads();

    int w = t >> 6, lane = t & 63;
    int l15 = lane & 15, lh = lane >> 4;
    unsigned mw[7];
    #pragma unroll
    for (int i = 0; i < 7; ++i) mw[i] = mword[i];
    short* Pw = &Pl[w][0];

    for (int qf = w; qf < 13; qf += 4) {
        int qbase = qf * 16;
        int q = qbase + l15;
        const short* qptr = qkv + (size_t)(b * 197 + q) * 2304 + h * 64;
        s16x8 bq0 = *(const s16x8*)(qptr + lh * 8);
        s16x8 bq1 = *(const s16x8*)(qptr + 32 + lh * 8);

        f32x4 sacc[14];
        #pragma unroll
        for (int mf = 0; mf < 14; ++mf) sacc[mf] = (f32x4){0.f, 0.f, 0.f, 0.f};
        #pragma unroll
        for (int mf = 0; mf < 14; ++mf) {
            int row = mf * 16 + l15;
            s16x8 a0 = *(const s16x8*)&Kl[(row * 8 + (lh ^ (row & 7))) * 8];
            s16x8 a1 = *(const s16x8*)&Kl[(row * 8 + ((4 + lh) ^ (row & 7))) * 8];
            sacc[mf] = __builtin_amdgcn_mfma_f32_16x16x32_bf16(a0, bq0, sacc[mf], 0, 0, 0);
            sacc[mf] = __builtin_amdgcn_mfma_f32_16x16x32_bf16(a1, bq1, sacc[mf], 0, 0, 0);
        }
        float m = -1e30f;
        #pragma unroll
        for (int mf = 0; mf < 14; ++mf) {
            #pragma unroll
            for (int r = 0; r < 4; ++r) {
                int k = mf * 16 + lh * 4 + r;
                int keep = (mw[k >> 5] >> (k & 31)) & 1;
                float lg = keep ? sacc[mf][r] * SCALE : -1e30f;
                sacc[mf][r] = lg;
                m = fmaxf(m, lg);
            }
        }
        m = fmaxf(m, __shfl_xor(m, 16));
        m = fmaxf(m, __shfl_xor(m, 32));
        float sum = 0.f;
        #pragma unroll
        for (int mf = 0; mf < 14; ++mf) {
            #pragma unroll
            for (int r = 0; r < 4; ++r) {
                float p = expf(sacc[mf][r] - m);
                sum += p;
                sacc[mf][r] = p;
            }
        }
        sum += __shfl_xor(sum, 16);
        sum += __shfl_xor(sum, 32);
        float inv = 1.f / sum;
        if (saveCls && qf == 0 && l15 == 0) {
            #pragma unroll
            for (int mf = 0; mf < 14; ++mf)
                #pragma unroll
                for (int r = 0; r < 4; ++r) {
                    int k = mf * 16 + lh * 4 + r;
                    if (k < 197) cls_row[((size_t)b * 12 + h) * 197 + k] = sacc[mf][r] * inv;
                }
        }
        #pragma unroll
        for (int mf = 0; mf < 14; ++mf) {
            s16x4 pk;
            #pragma unroll
            for (int r = 0; r < 4; ++r) {
                __hip_bfloat16 hb = __float2bfloat16(sacc[mf][r] * inv);
                pk[r] = *(short*)&hb;
            }
            int slot = l15 * 32 + ((mf * 2 + (lh >> 1)) ^ (l15 & 7));
            *(s16x4*)&Pw[slot * 8 + (lh & 1) * 4] = pk;
        }
        f32x4 oacc[4];
        #pragma unroll
        for (int nf = 0; nf < 4; ++nf) oacc[nf] = (f32x4){0.f, 0.f, 0.f, 0.f};
        #pragma unroll
        for (int ks = 0; ks < 7; ++ks) {
            int c = ks * 4 + lh;
            s16x8 pa = *(const s16x8*)&Pw[(l15 * 32 + (c ^ (l15 & 7))) * 8];
            #pragma unroll
            for (int nf = 0; nf < 4; ++nf) {
                int d = nf * 16 + l15;
                s16x8 bv = *(const s16x8*)&Vt[(d * 32 + (c ^ (d & 7))) * 8];
                oacc[nf] = __builtin_amdgcn_mfma_f32_16x16x32_bf16(pa, bv, oacc[nf], 0, 0, 0);
            }
        }
        #pragma unroll
        for (int nf = 0; nf < 4; ++nf) {
            #pragma unroll
            for (int r = 0; r < 4; ++r) {
                int q2 = qbase + lh * 4 + r;
                if (q2 < 197)
                    o[(size_t)(b * 197 + q2) * 768 + h * 64 + nf * 16 + l15] =
                        __float2bfloat16(oacc[nf][r]);
            }
        }
    }
}

// ---------------- ATS ----------------
__global__ void cls_scores(const float* __restrict__ x, const float* __restrict__ cls_row,
                           float* __restrict__ raw) {
    int bn = blockIdx.x;
    int b = bn / 196, n = bn % 196;
    const float* xr = x + ((size_t)b * 197 + 1 + n) * 768;
    int t = threadIdx.x;
    float s2 = 0.f;
    for (int c = t; c < 768; c += 256) { float v = xr[c]; s2 += v * v; }
    __shared__ float r[256];
    r[t] = s2; __syncthreads();
    for (int off = 128; off > 0; off >>= 1) {
        if (t < off) r[t] += r[t + off];
        __syncthreads();
    }
    if (t == 0) {
        float ca = 0.f;
        for (int h = 0; h < 12; ++h) ca += cls_row[((size_t)b * 12 + h) * 197 + 1 + n];
        raw[bn] = (ca * (1.f / 12.f)) * sqrtf(r[0]);
    }
}

__global__ void ats_mask_kernel(const float* __restrict__ raw, int* __restrict__ key_mask) {
    int b = blockIdx.x, t = threadIdx.x;
    __shared__ float s[196];
    __shared__ float ssorted[196];
    __shared__ int keep[196];
    __shared__ float red[256];
    float v = (t < 196) ? raw[b * 196 + t] : 0.f;
    red[t] = v; __syncthreads();
    for (int off = 128; off > 0; off >>= 1) {
        if (t < off) red[t] += red[t + off];
        __syncthreads();
    }
    float total = red[0];
    if (t < 196) s[t] = v / (total + 1e-12f);
    __syncthreads();
    int rk = 0;
    if (t < 196) {
        float mys = s[t];
        for (int j = 0; j < 196; ++j) {
            float sj = s[j];
            rk += (sj > mys) || (sj == mys && j < t);
        }
        ssorted[rk] = mys;
    }
    __syncthreads();
    if (t == 0) {
        float c = 0.f;
        for (int k = 0; k < 196; ++k) {
            c += ssorted[k];
            keep[k] = (c <= 0.9f) || (k == 0);
        }
    }
    __syncthreads();
    if (t == 0) key_mask[b * 197] = 1;
    if (t < 196) key_mask[b * 197 + 1 + t] = keep[rk];
}

// ---------------- head: out[64,1000] = At^T @ W + b, At[768][64] ----------------
__global__ void gemm_head_t(const float* __restrict__ At, const float* __restrict__ W,
                            const float* __restrict__ bias, float* __restrict__ out) {
    int col = blockIdx.x;
    int t = threadIdx.x;
    int row = t & 63, part = t >> 6;
    float acc = 0.f;
    for (int i = 0; i < 192; ++i) {
        int k = part * 192 + i;
        acc += At[(size_t)k * 64 + row] * W[(size_t)k * 1000 + col];
    }
    __shared__ float red[256];
    red[t] = acc; __syncthreads();
    if (part == 0)
        out[(size_t)row * 1000 + col] = red[row] + red[64 + row] + red[128 + row] + red[192 + row]
                                        + bias[col];
}

// ---------------- launch ----------------
extern "C" void kernel_launch(void* const* d_in, const int* in_sizes, int n_in,
                              void* d_out, int out_size, void* d_ws, size_t ws_size,
                              hipStream_t stream) {
    const float* images  = (const float*)d_in[0];
    const float* patch_w = (const float*)d_in[1];
    const float* patch_b = (const float*)d_in[2];
    const float* cls_tok = (const float*)d_in[3];
    const float* pos_emb = (const float*)d_in[4];
    const float* e_p[12]; const float* l_p[12];
    for (int i = 0; i < 12; ++i) e_p[i] = (const float*)d_in[5 + i];
    for (int i = 0; i < 12; ++i) l_p[i] = (const float*)d_in[17 + i];
    const float* norm_g = (const float*)d_in[29];
    const float* norm_b = (const float*)d_in[30];
    const float* head_w = (const float*)d_in[31];
    const float* head_b = (const float*)d_in[32];
    float* out = (float*)d_out;

    float* ws = (float*)d_ws;
    size_t off = 0;
    float* x = ws + off; off += (size_t)MP * 768;
    __hip_bfloat16* ybf = (__hip_bfloat16*)(ws + off); off += (size_t)MP * 768 / 2;
    float* qh = ws + off; off += (size_t)MP * 3072;           // region: qbf / hbf / P (bf16)
    __hip_bfloat16* qbf = (__hip_bfloat16*)qh;
    __hip_bfloat16* P = (__hip_bfloat16*)qh;
    __hip_bfloat16* hbf = (__hip_bfloat16*)qh;
    __hip_bfloat16* wt = (__hip_bfloat16*)(ws + off); off += (size_t)7077888 / 2;
    __hip_bfloat16* pwb = (__hip_bfloat16*)(ws + off); off += (size_t)589824 / 2;
    float* clsrow = ws + off; off += (size_t)64 * 12 * 197;
    float* raw = ws + off; off += (size_t)64 * 196;
    float* At = ws + off; off += (size_t)768 * 64;
    int* kmask = (int*)(ws + off); off += (size_t)64 * 197;

    __hip_bfloat16* wt_qkv  = wt;
    __hip_bfloat16* wt_proj = wt_qkv + (size_t)2304 * 768;
    __hip_bfloat16* wt_fc1  = wt_proj + (size_t)768 * 768;
    __hip_bfloat16* wt_fc2  = wt_fc1 + (size_t)3072 * 768;

    zero_pad_rows<<<64, 768, 0, stream>>>(x);
    set_cls<<<64, 768, 0, stream>>>(cls_tok, pos_emb, x);
    cast_pw<<<2304, 256, 0, stream>>>(patch_w, pwb, 589824);
    im2col_kernel<<<MP, 256, 0, stream>>>(images, P);
    gemm_mfma<3, 768><<<dim3(6, 99), 256, 0, stream>>>(P, pwb, patch_b, nullptr, x, nullptr,
                                                       pos_emb, 768);

    for (int blk = 0; blk < 12; ++blk) {
        bool early = blk < 9;
        int i = early ? blk : blk - 9;
        const float* const* p = early ? e_p : l_p;
        const float* ln1g = p[0] + (size_t)i * 768;
        const float* ln1b = p[1] + (size_t)i * 768;
        const float* qkvw = p[2] + (size_t)i * 768 * 2304;
        const float* qkvb = p[3] + (size_t)i * 2304;
        const float* projw = p[4] + (size_t)i * 768 * 768;
        const float* projb = p[5] + (size_t)i * 768;
        const float* ln2g = p[6] + (size_t)i * 768;
        const float* ln2b = p[7] + (size_t)i * 768;
        const float* fc1w = p[8] + (size_t)i * 768 * 3072;
        const float* fc1b = p[9] + (size_t)i * 3072;
        const float* fc2w = p[10] + (size_t)i * 3072 * 768;
        const float* fc2b = p[11] + (size_t)i * 768;
        int useMask = early ? 0 : 1;
        int saveCls = (early && i == 8) ? 1 : 0;

        transpose_cast_all<<<6912, dim3(32, 8), 0, stream>>>(qkvw, projw, fc1w, fc2w, wt);

        ln_bf16<<<MP, 256, 0, stream>>>(x, ln1g, ln1b, ybf);
        gemm_mfma<4, 768><<<dim3(18, 99), 256, 0, stream>>>(ybf, wt_qkv, qkvb, nullptr, nullptr,
                                                            qbf, nullptr, 2304);
        attn_mfma<<<dim3(12, 64), 256, 0, stream>>>(qbf, kmask, ybf, clsrow, useMask, saveCls);
        gemm_mfma<1, 768><<<dim3(6, 99), 256, 0, stream>>>(ybf, wt_proj, projb, x, x, nullptr,
                                                           nullptr, 768);
        ln_bf16<<<MP, 256, 0, stream>>>(x, ln2g, ln2b, ybf);
        gemm_mfma<2, 768><<<dim3(24, 99), 256, 0, stream>>>(ybf, wt_fc1, fc1b, nullptr, nullptr,
                                                            hbf, nullptr, 3072);
        gemm_mfma<1, 3072><<<dim3(6, 99), 256, 0, stream>>>(hbf, wt_fc2, fc2b, x, x, nullptr,
                                                            nullptr, 768);

        if (saveCls) {
            cls_scores<<<12544, 256, 0, stream>>>(x, clsrow, raw);
            ats_mask_kernel<<<64, 256, 0, stream>>>(raw, kmask);
        }
    }

    ln_cls_t<<<64, 256, 0, stream>>>(x, norm_g, norm_b, At);
    gemm_head_t<<<1000, 256, 0, stream>>>(At, head_w, head_b, out);
}

// Round 10
// 4894.344 us; speedup vs baseline: 1.2079x; 1.2079x over previous
//
#include <hip/hip_runtime.h>
#include <hip/hip_bf16.h>
#include <math.h>

typedef __attribute__((ext_vector_type(8))) short s16x8;
typedef __attribute__((ext_vector_type(4))) short s16x4;
typedef __attribute__((ext_vector_type(4))) float f32x4;

#define MP 12672        // padded token rows: 99*128 (real 64*197=12608)
#define MREAL 12608
#define PROWS 12544     // 64*196 patch rows
#define SCALE 0.125f

__device__ __forceinline__ float gelu_exact(float z) {
    return 0.5f * z * (1.f + erff(z * 0.7071067811865475f));
}

// ---------------- small utility kernels ----------------
__global__ void zero_pad_rows(float* __restrict__ x) {
    int r = MREAL + blockIdx.x;
    x[(size_t)r * 768 + threadIdx.x] = 0.f;
}

__global__ void set_cls(const float* __restrict__ cls, const float* __restrict__ pos,
                        float* __restrict__ x) {
    int b = blockIdx.x, t = threadIdx.x;
    x[(size_t)b * 197 * 768 + t] = cls[t] + pos[t];
}

__global__ void cast_pw(const float* __restrict__ w, __hip_bfloat16* __restrict__ o, int n) {
    int i = blockIdx.x * 256 + threadIdx.x;
    if (i < n) o[i] = __float2bfloat16(w[i]);
}

__global__ void im2col_kernel(const float* __restrict__ img, __hip_bfloat16* __restrict__ P) {
    int row = blockIdx.x;
    int t = threadIdx.x;
    if (row >= PROWS) {
        for (int k = t; k < 768; k += 256) P[(size_t)row * 768 + k] = __float2bfloat16(0.f);
        return;
    }
    int b = row / 196, n = row % 196;
    int gh = n / 14, gw = n % 14;
    for (int k = t; k < 768; k += 256) {
        int c = k >> 8, rem = k & 255, p = rem >> 4, q = rem & 15;
        float v = img[((size_t)(b * 3 + c) * 224 + (gh * 16 + p)) * 224 + gw * 16 + q];
        P[(size_t)row * 768 + k] = __float2bfloat16(v);
    }
}

// all 4 per-layer weight transposes in ONE launch (6912 blocks of 32x8)
__global__ void transpose_cast_all(const float* __restrict__ qkvw,
                                   const float* __restrict__ projw,
                                   const float* __restrict__ fc1w,
                                   const float* __restrict__ fc2w,
                                   __hip_bfloat16* __restrict__ wt) {
    __shared__ float tile[32][33];
    int bid = blockIdx.x;
    const float* W; __hip_bfloat16* D; int K, N, tn;
    if (bid < 1728) { W = qkvw; D = wt; K = 768; N = 2304; tn = 72; }
    else if (bid < 2304) { bid -= 1728; W = projw; D = wt + 1769472; K = 768; N = 768; tn = 24; }
    else if (bid < 4608) { bid -= 2304; W = fc1w; D = wt + 2359296; K = 768; N = 3072; tn = 96; }
    else { bid -= 4608; W = fc2w; D = wt + 4718592; K = 3072; N = 768; tn = 24; }
    int n0 = (bid % tn) * 32, k0 = (bid / tn) * 32;
    int tx = threadIdx.x, ty = threadIdx.y;
    #pragma unroll
    for (int i = 0; i < 4; ++i)
        tile[ty + i * 8][tx] = W[(size_t)(k0 + ty + i * 8) * N + n0 + tx];
    __syncthreads();
    #pragma unroll
    for (int i = 0; i < 4; ++i)
        D[(size_t)(n0 + ty + i * 8) * K + k0 + tx] = __float2bfloat16(tile[tx][ty + i * 8]);
}

// ---------------- layernorm ----------------
__global__ void ln_bf16(const float* __restrict__ x, const float* __restrict__ g,
                        const float* __restrict__ bia, __hip_bfloat16* __restrict__ y) {
    int row = blockIdx.x;
    const float* xr = x + (size_t)row * 768;
    __hip_bfloat16* yr = y + (size_t)row * 768;
    int t = threadIdx.x;
    float v[3];
    float s = 0.f, s2 = 0.f;
    #pragma unroll
    for (int i = 0; i < 3; ++i) { v[i] = xr[t + 256 * i]; s += v[i]; s2 += v[i] * v[i]; }
    __shared__ float r1[256], r2[256];
    r1[t] = s; r2[t] = s2; __syncthreads();
    for (int off = 128; off > 0; off >>= 1) {
        if (t < off) { r1[t] += r1[t + off]; r2[t] += r2[t + off]; }
        __syncthreads();
    }
    float mean = r1[0] * (1.f / 768.f);
    float var = r2[0] * (1.f / 768.f) - mean * mean;
    float rs = rsqrtf(var + 1e-6f);
    #pragma unroll
    for (int i = 0; i < 3; ++i) {
        int c = t + 256 * i;
        yr[c] = __float2bfloat16((v[i] - mean) * rs * g[c] + bia[c]);
    }
}

// final LN on the 64 CLS rows, output TRANSPOSED fp32 At[768][64]
__global__ void ln_cls_t(const float* __restrict__ x, const float* __restrict__ g,
                         const float* __restrict__ bia, float* __restrict__ At) {
    int b = blockIdx.x;
    const float* xr = x + (size_t)b * 197 * 768;
    int t = threadIdx.x;
    float v[3];
    float s = 0.f, s2 = 0.f;
    #pragma unroll
    for (int i = 0; i < 3; ++i) { v[i] = xr[t + 256 * i]; s += v[i]; s2 += v[i] * v[i]; }
    __shared__ float r1[256], r2[256];
    r1[t] = s; r2[t] = s2; __syncthreads();
    for (int off = 128; off > 0; off >>= 1) {
        if (t < off) { r1[t] += r1[t + off]; r2[t] += r2[t + off]; }
        __syncthreads();
    }
    float mean = r1[0] * (1.f / 768.f);
    float var = r2[0] * (1.f / 768.f) - mean * mean;
    float rs = rsqrtf(var + 1e-6f);
    #pragma unroll
    for (int i = 0; i < 3; ++i) {
        int c = t + 256 * i;
        At[(size_t)c * 64 + b] = (v[i] - mean) * rs * g[c] + bia[c];
    }
}

// ---------------- bf16 MFMA GEMM (proven round-6 config: runtime K, 128x128, 4 waves) ----------------
// EPI: 0 = bias -> f32   1 = bias + res -> f32   2 = bias + gelu -> bf16
//      3 = patch-embed remap (+pos) -> f32       4 = bias -> bf16
template <int EPI>
__global__ __launch_bounds__(256)
void gemm_mfma(const __hip_bfloat16* __restrict__ A,
               const __hip_bfloat16* __restrict__ Bt,
               const float* __restrict__ bias,
               const float* res, float* Cf, __hip_bfloat16* Cb,
               const float* __restrict__ pos,
               int Nc, int K) {
    __shared__ short As[8192];
    __shared__ short Bs[8192];
    int tid = threadIdx.x;
    int lane = tid & 63, w = tid >> 6;
    int wr = w >> 1, wc = w & 1;
    // XCD-aware bijective block swizzle (m204)
    int nwg = gridDim.x * gridDim.y;
    int bid = blockIdx.y * gridDim.x + blockIdx.x;
    int xcd = bid & 7, idx = bid >> 3;
    int qq = nwg >> 3, rr = nwg & 7;
    int swz = (xcd < rr ? xcd * (qq + 1) : rr * (qq + 1) + (xcd - rr) * qq) + idx;
    int bm = (swz / gridDim.x) * 128, bn = (swz % gridDim.x) * 128;
    int l15 = lane & 15, lh = lane >> 4;
    f32x4 acc[4][4] = {};
    for (int k0 = 0; k0 < K; k0 += 64) {
        #pragma unroll
        for (int q = 0; q < 4; ++q) {
            int S = (w * 4 + q) * 64 + lane;
            int row = S >> 3;
            int c = (S & 7) ^ (row & 7);
            const __hip_bfloat16* sA = A + (size_t)(bm + row) * K + (k0 + c * 8);
            const __hip_bfloat16* sB = Bt + (size_t)(bn + row) * K + (k0 + c * 8);
            __builtin_amdgcn_global_load_lds(
                (const __attribute__((address_space(1))) void*)sA,
                (__attribute__((address_space(3))) void*)&As[(w * 4 + q) * 512], 16, 0, 0);
            __builtin_amdgcn_global_load_lds(
                (const __attribute__((address_space(1))) void*)sB,
                (__attribute__((address_space(3))) void*)&Bs[(w * 4 + q) * 512], 16, 0, 0);
        }
        __syncthreads();
        #pragma unroll
        for (int ks = 0; ks < 2; ++ks) {
            s16x8 av[4], bv[4];
            int c = ks * 4 + lh;
            #pragma unroll
            for (int i = 0; i < 4; ++i) {
                int ra = wr * 64 + i * 16 + l15;
                av[i] = *(const s16x8*)&As[(ra * 8 + (c ^ (ra & 7))) * 8];
                int rb = wc * 64 + i * 16 + l15;
                bv[i] = *(const s16x8*)&Bs[(rb * 8 + (c ^ (rb & 7))) * 8];
            }
            #pragma unroll
            for (int i = 0; i < 4; ++i)
                #pragma unroll
                for (int j = 0; j < 4; ++j)
                    acc[i][j] = __builtin_amdgcn_mfma_f32_16x16x32_bf16(av[i], bv[j], acc[i][j], 0, 0, 0);
        }
        __syncthreads();
    }
    #pragma unroll
    for (int i = 0; i < 4; ++i) {
        #pragma unroll
        for (int j = 0; j < 4; ++j) {
            int colg = bn + wc * 64 + j * 16 + l15;
            float bcol = bias[colg];
            #pragma unroll
            for (int r = 0; r < 4; ++r) {
                int rowg = bm + wr * 64 + i * 16 + lh * 4 + r;
                float v = acc[i][j][r] + bcol;
                if (EPI == 0) {
                    Cf[(size_t)rowg * Nc + colg] = v;
                } else if (EPI == 1) {
                    Cf[(size_t)rowg * Nc + colg] = v + res[(size_t)rowg * Nc + colg];
                } else if (EPI == 2) {
                    Cb[(size_t)rowg * Nc + colg] = __float2bfloat16(gelu_exact(v));
                } else if (EPI == 4) {
                    Cb[(size_t)rowg * Nc + colg] = __float2bfloat16(v);
                } else {
                    if (rowg < PROWS) {
                        int b = rowg / 196, n = rowg % 196;
                        Cf[((size_t)b * 197 + 1 + n) * 768 + colg] = v + pos[(size_t)(1 + n) * 768 + colg];
                    }
                }
            }
        }
    }
}

// ---------------- MFMA flash attention ----------------
// grid (h=12, b=64), 256 threads = 4 waves. Swapped QK^T; 4-lane softmax reduce.
__global__ __launch_bounds__(256)
void attn_mfma(const __hip_bfloat16* __restrict__ qkvp, const int* __restrict__ key_mask,
               __hip_bfloat16* __restrict__ o, float* __restrict__ cls_row,
               int useMask, int saveCls) {
    int h = blockIdx.x, b = blockIdx.y;
    __shared__ short Kl[224 * 64];
    __shared__ short Vt[64 * 256];
    __shared__ short Pl[4][4096];
    __shared__ unsigned mword[7];
    const short* qkv = (const short*)qkvp;
    int t = threadIdx.x;

    if (t < 7) {
        unsigned wb = 0;
        for (int j = 0; j < 32; ++j) {
            int k = t * 32 + j;
            int bit = (k < 197) ? (useMask ? (key_mask[b * 197 + k] != 0) : 1) : 0;
            wb |= (unsigned)bit << j;
        }
        mword[t] = wb;
    }
    {
        int c = t & 7, kr0 = t >> 3;
        for (int it = 0; it < 7; ++it) {
            int krow = kr0 + it * 32;
            s16x8 v;
            if (krow < 197) {
                v = *(const s16x8*)(qkv + (size_t)(b * 197 + krow) * 2304 + 768 + h * 64 + c * 8);
            } else {
                #pragma unroll
                for (int j = 0; j < 8; ++j) v[j] = 0;
            }
            *(s16x8*)&Kl[(krow * 8 + (c ^ (krow & 7))) * 8] = v;
        }
    }
    {
        int d = t & 63, cb = t >> 6;
        for (int it = 0; it < 8; ++it) {
            int c = cb + it * 4;
            s16x8 v;
            #pragma unroll
            for (int j = 0; j < 8; ++j) {
                int k = c * 8 + j;
                v[j] = (k < 197) ? qkv[(size_t)(b * 197 + k) * 2304 + 1536 + h * 64 + d] : (short)0;
            }
            *(s16x8*)&Vt[(d * 32 + (c ^ (d & 7))) * 8] = v;
        }
    }
    __syncthreads();

    int w = t >> 6, lane = t & 63;
    int l15 = lane & 15, lh = lane >> 4;
    unsigned mw[7];
    #pragma unroll
    for (int i = 0; i < 7; ++i) mw[i] = mword[i];
    short* Pw = &Pl[w][0];

    for (int qf = w; qf < 13; qf += 4) {
        int qbase = qf * 16;
        int q = qbase + l15;
        const short* qptr = qkv + (size_t)(b * 197 + q) * 2304 + h * 64;
        s16x8 bq0 = *(const s16x8*)(qptr + lh * 8);
        s16x8 bq1 = *(const s16x8*)(qptr + 32 + lh * 8);

        f32x4 sacc[14];
        #pragma unroll
        for (int mf = 0; mf < 14; ++mf) sacc[mf] = (f32x4){0.f, 0.f, 0.f, 0.f};
        #pragma unroll
        for (int mf = 0; mf < 14; ++mf) {
            int row = mf * 16 + l15;
            s16x8 a0 = *(const s16x8*)&Kl[(row * 8 + (lh ^ (row & 7))) * 8];
            s16x8 a1 = *(const s16x8*)&Kl[(row * 8 + ((4 + lh) ^ (row & 7))) * 8];
            sacc[mf] = __builtin_amdgcn_mfma_f32_16x16x32_bf16(a0, bq0, sacc[mf], 0, 0, 0);
            sacc[mf] = __builtin_amdgcn_mfma_f32_16x16x32_bf16(a1, bq1, sacc[mf], 0, 0, 0);
        }
        float m = -1e30f;
        #pragma unroll
        for (int mf = 0; mf < 14; ++mf) {
            #pragma unroll
            for (int r = 0; r < 4; ++r) {
                int k = mf * 16 + lh * 4 + r;
                int keep = (mw[k >> 5] >> (k & 31)) & 1;
                float lg = keep ? sacc[mf][r] * SCALE : -1e30f;
                sacc[mf][r] = lg;
                m = fmaxf(m, lg);
            }
        }
        m = fmaxf(m, __shfl_xor(m, 16));
        m = fmaxf(m, __shfl_xor(m, 32));
        float sum = 0.f;
        #pragma unroll
        for (int mf = 0; mf < 14; ++mf) {
            #pragma unroll
            for (int r = 0; r < 4; ++r) {
                float p = expf(sacc[mf][r] - m);
                sum += p;
                sacc[mf][r] = p;
            }
        }
        sum += __shfl_xor(sum, 16);
        sum += __shfl_xor(sum, 32);
        float inv = 1.f / sum;
        if (saveCls && qf == 0 && l15 == 0) {
            #pragma unroll
            for (int mf = 0; mf < 14; ++mf)
                #pragma unroll
                for (int r = 0; r < 4; ++r) {
                    int k = mf * 16 + lh * 4 + r;
                    if (k < 197) cls_row[((size_t)b * 12 + h) * 197 + k] = sacc[mf][r] * inv;
                }
        }
        #pragma unroll
        for (int mf = 0; mf < 14; ++mf) {
            s16x4 pk;
            #pragma unroll
            for (int r = 0; r < 4; ++r) {
                __hip_bfloat16 hb = __float2bfloat16(sacc[mf][r] * inv);
                pk[r] = *(short*)&hb;
            }
            int slot = l15 * 32 + ((mf * 2 + (lh >> 1)) ^ (l15 & 7));
            *(s16x4*)&Pw[slot * 8 + (lh & 1) * 4] = pk;
        }
        f32x4 oacc[4];
        #pragma unroll
        for (int nf = 0; nf < 4; ++nf) oacc[nf] = (f32x4){0.f, 0.f, 0.f, 0.f};
        #pragma unroll
        for (int ks = 0; ks < 7; ++ks) {
            int c = ks * 4 + lh;
            s16x8 pa = *(const s16x8*)&Pw[(l15 * 32 + (c ^ (l15 & 7))) * 8];
            #pragma unroll
            for (int nf = 0; nf < 4; ++nf) {
                int d = nf * 16 + l15;
                s16x8 bv = *(const s16x8*)&Vt[(d * 32 + (c ^ (d & 7))) * 8];
                oacc[nf] = __builtin_amdgcn_mfma_f32_16x16x32_bf16(pa, bv, oacc[nf], 0, 0, 0);
            }
        }
        #pragma unroll
        for (int nf = 0; nf < 4; ++nf) {
            #pragma unroll
            for (int r = 0; r < 4; ++r) {
                int q2 = qbase + lh * 4 + r;
                if (q2 < 197)
                    o[(size_t)(b * 197 + q2) * 768 + h * 64 + nf * 16 + l15] =
                        __float2bfloat16(oacc[nf][r]);
            }
        }
    }
}

// ---------------- ATS ----------------
__global__ void cls_scores(const float* __restrict__ x, const float* __restrict__ cls_row,
                           float* __restrict__ raw) {
    int bn = blockIdx.x;
    int b = bn / 196, n = bn % 196;
    const float* xr = x + ((size_t)b * 197 + 1 + n) * 768;
    int t = threadIdx.x;
    float s2 = 0.f;
    for (int c = t; c < 768; c += 256) { float v = xr[c]; s2 += v * v; }
    __shared__ float r[256];
    r[t] = s2; __syncthreads();
    for (int off = 128; off > 0; off >>= 1) {
        if (t < off) r[t] += r[t + off];
        __syncthreads();
    }
    if (t == 0) {
        float ca = 0.f;
        for (int h = 0; h < 12; ++h) ca += cls_row[((size_t)b * 12 + h) * 197 + 1 + n];
        raw[bn] = (ca * (1.f / 12.f)) * sqrtf(r[0]);
    }
}

__global__ void ats_mask_kernel(const float* __restrict__ raw, int* __restrict__ key_mask) {
    int b = blockIdx.x, t = threadIdx.x;
    __shared__ float s[196];
    __shared__ float ssorted[196];
    __shared__ int keep[196];
    __shared__ float red[256];
    float v = (t < 196) ? raw[b * 196 + t] : 0.f;
    red[t] = v; __syncthreads();
    for (int off = 128; off > 0; off >>= 1) {
        if (t < off) red[t] += red[t + off];
        __syncthreads();
    }
    float total = red[0];
    if (t < 196) s[t] = v / (total + 1e-12f);
    __syncthreads();
    int rk = 0;
    if (t < 196) {
        float mys = s[t];
        for (int j = 0; j < 196; ++j) {
            float sj = s[j];
            rk += (sj > mys) || (sj == mys && j < t);
        }
        ssorted[rk] = mys;
    }
    __syncthreads();
    if (t == 0) {
        float c = 0.f;
        for (int k = 0; k < 196; ++k) {
            c += ssorted[k];
            keep[k] = (c <= 0.9f) || (k == 0);
        }
    }
    __syncthreads();
    if (t == 0) key_mask[b * 197] = 1;
    if (t < 196) key_mask[b * 197 + 1 + t] = keep[rk];
}

// ---------------- head: out[64,1000] = At^T @ W + b, At[768][64] ----------------
__global__ void gemm_head_t(const float* __restrict__ At, const float* __restrict__ W,
                            const float* __restrict__ bias, float* __restrict__ out) {
    int col = blockIdx.x;
    int t = threadIdx.x;
    int row = t & 63, part = t >> 6;
    float acc = 0.f;
    for (int i = 0; i < 192; ++i) {
        int k = part * 192 + i;
        acc += At[(size_t)k * 64 + row] * W[(size_t)k * 1000 + col];
    }
    __shared__ float red[256];
    red[t] = acc; __syncthreads();
    if (part == 0)
        out[(size_t)row * 1000 + col] = red[row] + red[64 + row] + red[128 + row] + red[192 + row]
                                        + bias[col];
}

// ---------------- launch ----------------
extern "C" void kernel_launch(void* const* d_in, const int* in_sizes, int n_in,
                              void* d_out, int out_size, void* d_ws, size_t ws_size,
                              hipStream_t stream) {
    const float* images  = (const float*)d_in[0];
    const float* patch_w = (const float*)d_in[1];
    const float* patch_b = (const float*)d_in[2];
    const float* cls_tok = (const float*)d_in[3];
    const float* pos_emb = (const float*)d_in[4];
    const float* e_p[12]; const float* l_p[12];
    for (int i = 0; i < 12; ++i) e_p[i] = (const float*)d_in[5 + i];
    for (int i = 0; i < 12; ++i) l_p[i] = (const float*)d_in[17 + i];
    const float* norm_g = (const float*)d_in[29];
    const float* norm_b = (const float*)d_in[30];
    const float* head_w = (const float*)d_in[31];
    const float* head_b = (const float*)d_in[32];
    float* out = (float*)d_out;

    float* ws = (float*)d_ws;
    size_t off = 0;
    float* x = ws + off; off += (size_t)MP * 768;
    __hip_bfloat16* ybf = (__hip_bfloat16*)(ws + off); off += (size_t)MP * 768 / 2;
    float* qh = ws + off; off += (size_t)MP * 3072;           // region: qbf / hbf / P (bf16)
    __hip_bfloat16* qbf = (__hip_bfloat16*)qh;
    __hip_bfloat16* P = (__hip_bfloat16*)qh;
    __hip_bfloat16* hbf = (__hip_bfloat16*)qh;
    __hip_bfloat16* wt = (__hip_bfloat16*)(ws + off); off += (size_t)7077888 / 2;
    __hip_bfloat16* pwb = (__hip_bfloat16*)(ws + off); off += (size_t)589824 / 2;
    float* clsrow = ws + off; off += (size_t)64 * 12 * 197;
    float* raw = ws + off; off += (size_t)64 * 196;
    float* At = ws + off; off += (size_t)768 * 64;
    int* kmask = (int*)(ws + off); off += (size_t)64 * 197;

    __hip_bfloat16* wt_qkv  = wt;
    __hip_bfloat16* wt_proj = wt_qkv + (size_t)2304 * 768;
    __hip_bfloat16* wt_fc1  = wt_proj + (size_t)768 * 768;
    __hip_bfloat16* wt_fc2  = wt_fc1 + (size_t)3072 * 768;

    zero_pad_rows<<<64, 768, 0, stream>>>(x);
    set_cls<<<64, 768, 0, stream>>>(cls_tok, pos_emb, x);
    cast_pw<<<2304, 256, 0, stream>>>(patch_w, pwb, 589824);
    im2col_kernel<<<MP, 256, 0, stream>>>(images, P);
    gemm_mfma<3><<<dim3(6, 99), 256, 0, stream>>>(P, pwb, patch_b, nullptr, x, nullptr,
                                                  pos_emb, 768, 768);

    for (int blk = 0; blk < 12; ++blk) {
        bool early = blk < 9;
        int i = early ? blk : blk - 9;
        const float* const* p = early ? e_p : l_p;
        const float* ln1g = p[0] + (size_t)i * 768;
        const float* ln1b = p[1] + (size_t)i * 768;
        const float* qkvw = p[2] + (size_t)i * 768 * 2304;
        const float* qkvb = p[3] + (size_t)i * 2304;
        const float* projw = p[4] + (size_t)i * 768 * 768;
        const float* projb = p[5] + (size_t)i * 768;
        const float* ln2g = p[6] + (size_t)i * 768;
        const float* ln2b = p[7] + (size_t)i * 768;
        const float* fc1w = p[8] + (size_t)i * 768 * 3072;
        const float* fc1b = p[9] + (size_t)i * 3072;
        const float* fc2w = p[10] + (size_t)i * 3072 * 768;
        const float* fc2b = p[11] + (size_t)i * 768;
        int useMask = early ? 0 : 1;
        int saveCls = (early && i == 8) ? 1 : 0;

        transpose_cast_all<<<6912, dim3(32, 8), 0, stream>>>(qkvw, projw, fc1w, fc2w, wt);

        ln_bf16<<<MP, 256, 0, stream>>>(x, ln1g, ln1b, ybf);
        gemm_mfma<4><<<dim3(18, 99), 256, 0, stream>>>(ybf, wt_qkv, qkvb, nullptr, nullptr, qbf,
                                                       nullptr, 2304, 768);
        attn_mfma<<<dim3(12, 64), 256, 0, stream>>>(qbf, kmask, ybf, clsrow, useMask, saveCls);
        gemm_mfma<1><<<dim3(6, 99), 256, 0, stream>>>(ybf, wt_proj, projb, x, x, nullptr,
                                                      nullptr, 768, 768);
        ln_bf16<<<MP, 256, 0, stream>>>(x, ln2g, ln2b, ybf);
        gemm_mfma<2><<<dim3(24, 99), 256, 0, stream>>>(ybf, wt_fc1, fc1b, nullptr, nullptr, hbf,
                                                       nullptr, 3072, 768);
        gemm_mfma<1><<<dim3(6, 99), 256, 0, stream>>>(hbf, wt_fc2, fc2b, x, x, nullptr,
                                                      nullptr, 768, 3072);

        if (saveCls) {
            cls_scores<<<12544, 256, 0, stream>>>(x, clsrow, raw);
            ats_mask_kernel<<<64, 256, 0, stream>>>(raw, kmask);
        }
    }

    ln_cls_t<<<64, 256, 0, stream>>>(x, norm_g, norm_b, At);
    gemm_head_t<<<1000, 256, 0, stream>>>(At, head_w, head_b, out);
}

// Round 11
// 4564.346 us; speedup vs baseline: 1.2952x; 1.0723x over previous
//
#include <hip/hip_runtime.h>
#include <hip/hip_bf16.h>
#include <math.h>

typedef __attribute__((ext_vector_type(8))) short s16x8;
typedef __attribute__((ext_vector_type(4))) short s16x4;
typedef __attribute__((ext_vector_type(4))) float f32x4;

#define MP 12672        // padded token rows: 99*128 (real 64*197=12608)
#define MREAL 12608
#define PROWS 12544     // 64*196 patch rows
#define SCALE 0.125f

__device__ __forceinline__ float gelu_exact(float z) {
    return 0.5f * z * (1.f + erff(z * 0.7071067811865475f));
}

// ---------------- small utility kernels ----------------
__global__ void zero_pad_rows(float* __restrict__ x) {
    int r = MREAL + blockIdx.x;
    x[(size_t)r * 768 + threadIdx.x] = 0.f;
}

__global__ void set_cls(const float* __restrict__ cls, const float* __restrict__ pos,
                        float* __restrict__ x) {
    int b = blockIdx.x, t = threadIdx.x;
    x[(size_t)b * 197 * 768 + t] = cls[t] + pos[t];
}

__global__ void cast_pw(const float* __restrict__ w, __hip_bfloat16* __restrict__ o, int n) {
    int i = blockIdx.x * 256 + threadIdx.x;
    if (i < n) o[i] = __float2bfloat16(w[i]);
}

__global__ void im2col_kernel(const float* __restrict__ img, __hip_bfloat16* __restrict__ P) {
    int row = blockIdx.x;
    int t = threadIdx.x;
    if (row >= PROWS) {
        for (int k = t; k < 768; k += 256) P[(size_t)row * 768 + k] = __float2bfloat16(0.f);
        return;
    }
    int b = row / 196, n = row % 196;
    int gh = n / 14, gw = n % 14;
    for (int k = t; k < 768; k += 256) {
        int c = k >> 8, rem = k & 255, p = rem >> 4, q = rem & 15;
        float v = img[((size_t)(b * 3 + c) * 224 + (gh * 16 + p)) * 224 + gw * 16 + q];
        P[(size_t)row * 768 + k] = __float2bfloat16(v);
    }
}

// all 4 per-layer weight transposes in ONE launch (6912 blocks of 32x8)
__global__ void transpose_cast_all(const float* __restrict__ qkvw,
                                   const float* __restrict__ projw,
                                   const float* __restrict__ fc1w,
                                   const float* __restrict__ fc2w,
                                   __hip_bfloat16* __restrict__ wt) {
    __shared__ float tile[32][33];
    int bid = blockIdx.x;
    const float* W; __hip_bfloat16* D; int K, N, tn;
    if (bid < 1728) { W = qkvw; D = wt; K = 768; N = 2304; tn = 72; }
    else if (bid < 2304) { bid -= 1728; W = projw; D = wt + 1769472; K = 768; N = 768; tn = 24; }
    else if (bid < 4608) { bid -= 2304; W = fc1w; D = wt + 2359296; K = 768; N = 3072; tn = 96; }
    else { bid -= 4608; W = fc2w; D = wt + 4718592; K = 3072; N = 768; tn = 24; }
    int n0 = (bid % tn) * 32, k0 = (bid / tn) * 32;
    int tx = threadIdx.x, ty = threadIdx.y;
    #pragma unroll
    for (int i = 0; i < 4; ++i)
        tile[ty + i * 8][tx] = W[(size_t)(k0 + ty + i * 8) * N + n0 + tx];
    __syncthreads();
    #pragma unroll
    for (int i = 0; i < 4; ++i)
        D[(size_t)(n0 + ty + i * 8) * K + k0 + tx] = __float2bfloat16(tile[tx][ty + i * 8]);
}

// ---------------- layernorm: one WAVE per row, f32x4 loads, shuffle reduce ----------------
__global__ void ln_bf16_w(const float* __restrict__ x, const float* __restrict__ g,
                          const float* __restrict__ bia, __hip_bfloat16* __restrict__ y) {
    int row = blockIdx.x * 4 + (threadIdx.x >> 6);
    int lane = threadIdx.x & 63;
    const float* xr = x + (size_t)row * 768;
    f32x4 v[3];
    float s = 0.f, s2 = 0.f;
    #pragma unroll
    for (int i = 0; i < 3; ++i) {
        v[i] = *(const f32x4*)&xr[lane * 4 + i * 256];
        #pragma unroll
        for (int j = 0; j < 4; ++j) { s += v[i][j]; s2 += v[i][j] * v[i][j]; }
    }
    #pragma unroll
    for (int off = 1; off < 64; off <<= 1) { s += __shfl_xor(s, off); s2 += __shfl_xor(s2, off); }
    float mean = s * (1.f / 768.f);
    float var = s2 * (1.f / 768.f) - mean * mean;
    float rs = rsqrtf(var + 1e-6f);
    #pragma unroll
    for (int i = 0; i < 3; ++i) {
        int c = lane * 4 + i * 256;
        f32x4 gg = *(const f32x4*)&g[c];
        f32x4 bb = *(const f32x4*)&bia[c];
        s16x4 o;
        #pragma unroll
        for (int j = 0; j < 4; ++j) {
            __hip_bfloat16 hb = __float2bfloat16((v[i][j] - mean) * rs * gg[j] + bb[j]);
            o[j] = *(short*)&hb;
        }
        *(s16x4*)&y[(size_t)row * 768 + c] = o;
    }
}

// final LN on the 64 CLS rows, output TRANSPOSED fp32 At[768][64]
__global__ void ln_cls_t(const float* __restrict__ x, const float* __restrict__ g,
                         const float* __restrict__ bia, float* __restrict__ At) {
    int b = blockIdx.x;
    const float* xr = x + (size_t)b * 197 * 768;
    int t = threadIdx.x;
    float v[3];
    float s = 0.f, s2 = 0.f;
    #pragma unroll
    for (int i = 0; i < 3; ++i) { v[i] = xr[t + 256 * i]; s += v[i]; s2 += v[i] * v[i]; }
    __shared__ float r1[256], r2[256];
    r1[t] = s; r2[t] = s2; __syncthreads();
    for (int off = 128; off > 0; off >>= 1) {
        if (t < off) { r1[t] += r1[t + off]; r2[t] += r2[t + off]; }
        __syncthreads();
    }
    float mean = r1[0] * (1.f / 768.f);
    float var = r2[0] * (1.f / 768.f) - mean * mean;
    float rs = rsqrtf(var + 1e-6f);
    #pragma unroll
    for (int i = 0; i < 3; ++i) {
        int c = t + 256 * i;
        At[(size_t)c * 64 + b] = (v[i] - mean) * rs * g[c] + bia[c];
    }
}

// ---------------- bf16 MFMA GEMM (FROZEN round-6 config: runtime K, 128x128, 4 waves) ----------------
// EPI: 0 = bias -> f32   1 = bias + res -> f32   2 = bias + gelu -> bf16
//      3 = patch-embed remap (+pos) -> f32       4 = bias -> bf16
template <int EPI>
__global__ __launch_bounds__(256)
void gemm_mfma(const __hip_bfloat16* __restrict__ A,
               const __hip_bfloat16* __restrict__ Bt,
               const float* __restrict__ bias,
               const float* res, float* Cf, __hip_bfloat16* Cb,
               const float* __restrict__ pos,
               int Nc, int K) {
    __shared__ short As[8192];
    __shared__ short Bs[8192];
    int tid = threadIdx.x;
    int lane = tid & 63, w = tid >> 6;
    int wr = w >> 1, wc = w & 1;
    // XCD-aware bijective block swizzle (m204)
    int nwg = gridDim.x * gridDim.y;
    int bid = blockIdx.y * gridDim.x + blockIdx.x;
    int xcd = bid & 7, idx = bid >> 3;
    int qq = nwg >> 3, rr = nwg & 7;
    int swz = (xcd < rr ? xcd * (qq + 1) : rr * (qq + 1) + (xcd - rr) * qq) + idx;
    int bm = (swz / gridDim.x) * 128, bn = (swz % gridDim.x) * 128;
    int l15 = lane & 15, lh = lane >> 4;
    f32x4 acc[4][4] = {};
    for (int k0 = 0; k0 < K; k0 += 64) {
        #pragma unroll
        for (int q = 0; q < 4; ++q) {
            int S = (w * 4 + q) * 64 + lane;
            int row = S >> 3;
            int c = (S & 7) ^ (row & 7);
            const __hip_bfloat16* sA = A + (size_t)(bm + row) * K + (k0 + c * 8);
            const __hip_bfloat16* sB = Bt + (size_t)(bn + row) * K + (k0 + c * 8);
            __builtin_amdgcn_global_load_lds(
                (const __attribute__((address_space(1))) void*)sA,
                (__attribute__((address_space(3))) void*)&As[(w * 4 + q) * 512], 16, 0, 0);
            __builtin_amdgcn_global_load_lds(
                (const __attribute__((address_space(1))) void*)sB,
                (__attribute__((address_space(3))) void*)&Bs[(w * 4 + q) * 512], 16, 0, 0);
        }
        __syncthreads();
        #pragma unroll
        for (int ks = 0; ks < 2; ++ks) {
            s16x8 av[4], bv[4];
            int c = ks * 4 + lh;
            #pragma unroll
            for (int i = 0; i < 4; ++i) {
                int ra = wr * 64 + i * 16 + l15;
                av[i] = *(const s16x8*)&As[(ra * 8 + (c ^ (ra & 7))) * 8];
                int rb = wc * 64 + i * 16 + l15;
                bv[i] = *(const s16x8*)&Bs[(rb * 8 + (c ^ (rb & 7))) * 8];
            }
            #pragma unroll
            for (int i = 0; i < 4; ++i)
                #pragma unroll
                for (int j = 0; j < 4; ++j)
                    acc[i][j] = __builtin_amdgcn_mfma_f32_16x16x32_bf16(av[i], bv[j], acc[i][j], 0, 0, 0);
        }
        __syncthreads();
    }
    #pragma unroll
    for (int i = 0; i < 4; ++i) {
        #pragma unroll
        for (int j = 0; j < 4; ++j) {
            int colg = bn + wc * 64 + j * 16 + l15;
            float bcol = bias[colg];
            #pragma unroll
            for (int r = 0; r < 4; ++r) {
                int rowg = bm + wr * 64 + i * 16 + lh * 4 + r;
                float v = acc[i][j][r] + bcol;
                if (EPI == 0) {
                    Cf[(size_t)rowg * Nc + colg] = v;
                } else if (EPI == 1) {
                    Cf[(size_t)rowg * Nc + colg] = v + res[(size_t)rowg * Nc + colg];
                } else if (EPI == 2) {
                    Cb[(size_t)rowg * Nc + colg] = __float2bfloat16(gelu_exact(v));
                } else if (EPI == 4) {
                    Cb[(size_t)rowg * Nc + colg] = __float2bfloat16(v);
                } else {
                    if (rowg < PROWS) {
                        int b = rowg / 196, n = rowg % 196;
                        Cf[((size_t)b * 197 + 1 + n) * 768 + colg] = v + pos[(size_t)(1 + n) * 768 + colg];
                    }
                }
            }
        }
    }
}

// ---------------- MFMA flash attention: 8 waves per (b,h) ----------------
// grid (h=12, b=64), 512 threads = 8 waves (2 waves/SIMD vs 1 before).
// Per-wave compute identical to the verified 4-wave version; staging
// re-parameterized for 512 threads; Pl grown to 8 wave-slots (LDS 127KB).
__global__ __launch_bounds__(512)
void attn_mfma(const __hip_bfloat16* __restrict__ qkvp, const int* __restrict__ key_mask,
               __hip_bfloat16* __restrict__ o, float* __restrict__ cls_row,
               int useMask, int saveCls) {
    int h = blockIdx.x, b = blockIdx.y;
    __shared__ short Kl[224 * 64];
    __shared__ short Vt[64 * 256];
    __shared__ short Pl[8][4096];
    __shared__ unsigned mword[7];
    const short* qkv = (const short*)qkvp;
    int t = threadIdx.x;

    if (t < 7) {
        unsigned wb = 0;
        for (int j = 0; j < 32; ++j) {
            int k = t * 32 + j;
            int bit = (k < 197) ? (useMask ? (key_mask[b * 197 + k] != 0) : 1) : 0;
            wb |= (unsigned)bit << j;
        }
        mword[t] = wb;
    }
    // K staging: 512 threads = 64 rows x 8 d-octets per pass; 4 passes cover 224 rows
    {
        int c = t & 7, kr0 = t >> 3;          // kr0: 0..63
        for (int it = 0; it < 4; ++it) {
            int krow = kr0 + it * 64;
            if (krow < 224) {
                s16x8 v;
                if (krow < 197) {
                    v = *(const s16x8*)(qkv + (size_t)(b * 197 + krow) * 2304 + 768 + h * 64 + c * 8);
                } else {
                    #pragma unroll
                    for (int j = 0; j < 8; ++j) v[j] = 0;
                }
                *(s16x8*)&Kl[(krow * 8 + (c ^ (krow & 7))) * 8] = v;
            }
        }
    }
    // V staging (transpose): 512 threads = 64 d x 8 chunk-bases; 4 passes cover 32 chunks
    {
        int d = t & 63, cb = t >> 6;          // cb: 0..7
        for (int it = 0; it < 4; ++it) {
            int c = cb + it * 8;
            s16x8 v;
            #pragma unroll
            for (int j = 0; j < 8; ++j) {
                int k = c * 8 + j;
                v[j] = (k < 197) ? qkv[(size_t)(b * 197 + k) * 2304 + 1536 + h * 64 + d] : (short)0;
            }
            *(s16x8*)&Vt[(d * 32 + (c ^ (d & 7))) * 8] = v;
        }
    }
    __syncthreads();

    int w = t >> 6, lane = t & 63;
    int l15 = lane & 15, lh = lane >> 4;
    unsigned mw[7];
    #pragma unroll
    for (int i = 0; i < 7; ++i) mw[i] = mword[i];
    short* Pw = &Pl[w][0];

    for (int qf = w; qf < 13; qf += 8) {
        int qbase = qf * 16;
        int q = qbase + l15;
        const short* qptr = qkv + (size_t)(b * 197 + q) * 2304 + h * 64;
        s16x8 bq0 = *(const s16x8*)(qptr + lh * 8);
        s16x8 bq1 = *(const s16x8*)(qptr + 32 + lh * 8);

        f32x4 sacc[14];
        #pragma unroll
        for (int mf = 0; mf < 14; ++mf) sacc[mf] = (f32x4){0.f, 0.f, 0.f, 0.f};
        #pragma unroll
        for (int mf = 0; mf < 14; ++mf) {
            int row = mf * 16 + l15;
            s16x8 a0 = *(const s16x8*)&Kl[(row * 8 + (lh ^ (row & 7))) * 8];
            s16x8 a1 = *(const s16x8*)&Kl[(row * 8 + ((4 + lh) ^ (row & 7))) * 8];
            sacc[mf] = __builtin_amdgcn_mfma_f32_16x16x32_bf16(a0, bq0, sacc[mf], 0, 0, 0);
            sacc[mf] = __builtin_amdgcn_mfma_f32_16x16x32_bf16(a1, bq1, sacc[mf], 0, 0, 0);
        }
        float m = -1e30f;
        #pragma unroll
        for (int mf = 0; mf < 14; ++mf) {
            #pragma unroll
            for (int r = 0; r < 4; ++r) {
                int k = mf * 16 + lh * 4 + r;
                int keep = (mw[k >> 5] >> (k & 31)) & 1;
                float lg = keep ? sacc[mf][r] * SCALE : -1e30f;
                sacc[mf][r] = lg;
                m = fmaxf(m, lg);
            }
        }
        m = fmaxf(m, __shfl_xor(m, 16));
        m = fmaxf(m, __shfl_xor(m, 32));
        float sum = 0.f;
        #pragma unroll
        for (int mf = 0; mf < 14; ++mf) {
            #pragma unroll
            for (int r = 0; r < 4; ++r) {
                float p = expf(sacc[mf][r] - m);
                sum += p;
                sacc[mf][r] = p;
            }
        }
        sum += __shfl_xor(sum, 16);
        sum += __shfl_xor(sum, 32);
        float inv = 1.f / sum;
        if (saveCls && qf == 0 && l15 == 0) {
            #pragma unroll
            for (int mf = 0; mf < 14; ++mf)
                #pragma unroll
                for (int r = 0; r < 4; ++r) {
                    int k = mf * 16 + lh * 4 + r;
                    if (k < 197) cls_row[((size_t)b * 12 + h) * 197 + k] = sacc[mf][r] * inv;
                }
        }
        #pragma unroll
        for (int mf = 0; mf < 14; ++mf) {
            s16x4 pk;
            #pragma unroll
            for (int r = 0; r < 4; ++r) {
                __hip_bfloat16 hb = __float2bfloat16(sacc[mf][r] * inv);
                pk[r] = *(short*)&hb;
            }
            int slot = l15 * 32 + ((mf * 2 + (lh >> 1)) ^ (l15 & 7));
            *(s16x4*)&Pw[slot * 8 + (lh & 1) * 4] = pk;
        }
        f32x4 oacc[4];
        #pragma unroll
        for (int nf = 0; nf < 4; ++nf) oacc[nf] = (f32x4){0.f, 0.f, 0.f, 0.f};
        #pragma unroll
        for (int ks = 0; ks < 7; ++ks) {
            int c = ks * 4 + lh;
            s16x8 pa = *(const s16x8*)&Pw[(l15 * 32 + (c ^ (l15 & 7))) * 8];
            #pragma unroll
            for (int nf = 0; nf < 4; ++nf) {
                int d = nf * 16 + l15;
                s16x8 bv = *(const s16x8*)&Vt[(d * 32 + (c ^ (d & 7))) * 8];
                oacc[nf] = __builtin_amdgcn_mfma_f32_16x16x32_bf16(pa, bv, oacc[nf], 0, 0, 0);
            }
        }
        #pragma unroll
        for (int nf = 0; nf < 4; ++nf) {
            #pragma unroll
            for (int r = 0; r < 4; ++r) {
                int q2 = qbase + lh * 4 + r;
                if (q2 < 197)
                    o[(size_t)(b * 197 + q2) * 768 + h * 64 + nf * 16 + l15] =
                        __float2bfloat16(oacc[nf][r]);
            }
        }
    }
}

// ---------------- ATS ----------------
__global__ void cls_scores(const float* __restrict__ x, const float* __restrict__ cls_row,
                           float* __restrict__ raw) {
    int bn = blockIdx.x;
    int b = bn / 196, n = bn % 196;
    const float* xr = x + ((size_t)b * 197 + 1 + n) * 768;
    int t = threadIdx.x;
    float s2 = 0.f;
    for (int c = t; c < 768; c += 256) { float v = xr[c]; s2 += v * v; }
    __shared__ float r[256];
    r[t] = s2; __syncthreads();
    for (int off = 128; off > 0; off >>= 1) {
        if (t < off) r[t] += r[t + off];
        __syncthreads();
    }
    if (t == 0) {
        float ca = 0.f;
        for (int h = 0; h < 12; ++h) ca += cls_row[((size_t)b * 12 + h) * 197 + 1 + n];
        raw[bn] = (ca * (1.f / 12.f)) * sqrtf(r[0]);
    }
}

__global__ void ats_mask_kernel(const float* __restrict__ raw, int* __restrict__ key_mask) {
    int b = blockIdx.x, t = threadIdx.x;
    __shared__ float s[196];
    __shared__ float ssorted[196];
    __shared__ int keep[196];
    __shared__ float red[256];
    float v = (t < 196) ? raw[b * 196 + t] : 0.f;
    red[t] = v; __syncthreads();
    for (int off = 128; off > 0; off >>= 1) {
        if (t < off) red[t] += red[t + off];
        __syncthreads();
    }
    float total = red[0];
    if (t < 196) s[t] = v / (total + 1e-12f);
    __syncthreads();
    int rk = 0;
    if (t < 196) {
        float mys = s[t];
        for (int j = 0; j < 196; ++j) {
            float sj = s[j];
            rk += (sj > mys) || (sj == mys && j < t);
        }
        ssorted[rk] = mys;
    }
    __syncthreads();
    if (t == 0) {
        float c = 0.f;
        for (int k = 0; k < 196; ++k) {
            c += ssorted[k];
            keep[k] = (c <= 0.9f) || (k == 0);
        }
    }
    __syncthreads();
    if (t == 0) key_mask[b * 197] = 1;
    if (t < 196) key_mask[b * 197 + 1 + t] = keep[rk];
}

// ---------------- head: out[64,1000] = At^T @ W + b, At[768][64] ----------------
__global__ void gemm_head_t(const float* __restrict__ At, const float* __restrict__ W,
                            const float* __restrict__ bias, float* __restrict__ out) {
    int col = blockIdx.x;
    int t = threadIdx.x;
    int row = t & 63, part = t >> 6;
    float acc = 0.f;
    for (int i = 0; i < 192; ++i) {
        int k = part * 192 + i;
        acc += At[(size_t)k * 64 + row] * W[(size_t)k * 1000 + col];
    }
    __shared__ float red[256];
    red[t] = acc; __syncthreads();
    if (part == 0)
        out[(size_t)row * 1000 + col] = red[row] + red[64 + row] + red[128 + row] + red[192 + row]
                                        + bias[col];
}

// ---------------- launch ----------------
extern "C" void kernel_launch(void* const* d_in, const int* in_sizes, int n_in,
                              void* d_out, int out_size, void* d_ws, size_t ws_size,
                              hipStream_t stream) {
    const float* images  = (const float*)d_in[0];
    const float* patch_w = (const float*)d_in[1];
    const float* patch_b = (const float*)d_in[2];
    const float* cls_tok = (const float*)d_in[3];
    const float* pos_emb = (const float*)d_in[4];
    const float* e_p[12]; const float* l_p[12];
    for (int i = 0; i < 12; ++i) e_p[i] = (const float*)d_in[5 + i];
    for (int i = 0; i < 12; ++i) l_p[i] = (const float*)d_in[17 + i];
    const float* norm_g = (const float*)d_in[29];
    const float* norm_b = (const float*)d_in[30];
    const float* head_w = (const float*)d_in[31];
    const float* head_b = (const float*)d_in[32];
    float* out = (float*)d_out;

    float* ws = (float*)d_ws;
    size_t off = 0;
    float* x = ws + off; off += (size_t)MP * 768;
    __hip_bfloat16* ybf = (__hip_bfloat16*)(ws + off); off += (size_t)MP * 768 / 2;
    float* qh = ws + off; off += (size_t)MP * 3072;           // region: qbf / hbf / P (bf16)
    __hip_bfloat16* qbf = (__hip_bfloat16*)qh;
    __hip_bfloat16* P = (__hip_bfloat16*)qh;
    __hip_bfloat16* hbf = (__hip_bfloat16*)qh;
    __hip_bfloat16* wt = (__hip_bfloat16*)(ws + off); off += (size_t)7077888 / 2;
    __hip_bfloat16* pwb = (__hip_bfloat16*)(ws + off); off += (size_t)589824 / 2;
    float* clsrow = ws + off; off += (size_t)64 * 12 * 197;
    float* raw = ws + off; off += (size_t)64 * 196;
    float* At = ws + off; off += (size_t)768 * 64;
    int* kmask = (int*)(ws + off); off += (size_t)64 * 197;

    __hip_bfloat16* wt_qkv  = wt;
    __hip_bfloat16* wt_proj = wt_qkv + (size_t)2304 * 768;
    __hip_bfloat16* wt_fc1  = wt_proj + (size_t)768 * 768;
    __hip_bfloat16* wt_fc2  = wt_fc1 + (size_t)3072 * 768;

    zero_pad_rows<<<64, 768, 0, stream>>>(x);
    set_cls<<<64, 768, 0, stream>>>(cls_tok, pos_emb, x);
    cast_pw<<<2304, 256, 0, stream>>>(patch_w, pwb, 589824);
    im2col_kernel<<<MP, 256, 0, stream>>>(images, P);
    gemm_mfma<3><<<dim3(6, 99), 256, 0, stream>>>(P, pwb, patch_b, nullptr, x, nullptr,
                                                  pos_emb, 768, 768);

    for (int blk = 0; blk < 12; ++blk) {
        bool early = blk < 9;
        int i = early ? blk : blk - 9;
        const float* const* p = early ? e_p : l_p;
        const float* ln1g = p[0] + (size_t)i * 768;
        const float* ln1b = p[1] + (size_t)i * 768;
        const float* qkvw = p[2] + (size_t)i * 768 * 2304;
        const float* qkvb = p[3] + (size_t)i * 2304;
        const float* projw = p[4] + (size_t)i * 768 * 768;
        const float* projb = p[5] + (size_t)i * 768;
        const float* ln2g = p[6] + (size_t)i * 768;
        const float* ln2b = p[7] + (size_t)i * 768;
        const float* fc1w = p[8] + (size_t)i * 768 * 3072;
        const float* fc1b = p[9] + (size_t)i * 3072;
        const float* fc2w = p[10] + (size_t)i * 3072 * 768;
        const float* fc2b = p[11] + (size_t)i * 768;
        int useMask = early ? 0 : 1;
        int saveCls = (early && i == 8) ? 1 : 0;

        transpose_cast_all<<<6912, dim3(32, 8), 0, stream>>>(qkvw, projw, fc1w, fc2w, wt);

        ln_bf16_w<<<MP / 4, 256, 0, stream>>>(x, ln1g, ln1b, ybf);
        gemm_mfma<4><<<dim3(18, 99), 256, 0, stream>>>(ybf, wt_qkv, qkvb, nullptr, nullptr, qbf,
                                                       nullptr, 2304, 768);
        attn_mfma<<<dim3(12, 64), 512, 0, stream>>>(qbf, kmask, ybf, clsrow, useMask, saveCls);
        gemm_mfma<1><<<dim3(6, 99), 256, 0, stream>>>(ybf, wt_proj, projb, x, x, nullptr,
                                                      nullptr, 768, 768);
        ln_bf16_w<<<MP / 4, 256, 0, stream>>>(x, ln2g, ln2b, ybf);
        gemm_mfma<2><<<dim3(24, 99), 256, 0, stream>>>(ybf, wt_fc1, fc1b, nullptr, nullptr, hbf,
                                                       nullptr, 3072, 768);
        gemm_mfma<1><<<dim3(6, 99), 256, 0, stream>>>(hbf, wt_fc2, fc2b, x, x, nullptr,
                                                      nullptr, 768, 3072);

        if (saveCls) {
            cls_scores<<<12544, 256, 0, stream>>>(x, clsrow, raw);
            ats_mask_kernel<<<64, 256, 0, stream>>>(raw, kmask);
        }
    }

    ln_cls_t<<<64, 256, 0, stream>>>(x, norm_g, norm_b, At);
    gemm_head_t<<<1000, 256, 0, stream>>>(At, head_w, head_b, out);
}